// Round 1
// baseline (2403.214 us; speedup 1.0000x reference)
//
#include <hip/hip_runtime.h>

#define TM 128
#define TN 128
#define TKK 16
#define CAP 38000
#define NEGV -1e10f

// ---------------- Generic fp32 GEMM: C[z] = A[M,K(slice)] @ B[K,N] (+bias)(+relu) ----------
__global__ __launch_bounds__(256) void gemm_f32(
    const float* __restrict__ A, const float* __restrict__ B,
    const float* __restrict__ bias, float* __restrict__ C,
    int M, int N, int K, int ksplit, int relu)
{
    __shared__ float As[TKK][TM + 4];
    __shared__ float Bs[TKK][TN + 4];
    const int tid = threadIdx.x;
    const int tx = tid & 15, ty = tid >> 4;
    const int m0 = blockIdx.y * TM, n0 = blockIdx.x * TN;
    const int z = blockIdx.z;
    const int kstart = z * ksplit;
    const int kend = (kstart + ksplit < K) ? (kstart + ksplit) : K;
    float* Cz = C + (size_t)z * (size_t)M * (size_t)N;
    const bool nvec = ((N & 3) == 0);

    float acc[8][8];
#pragma unroll
    for (int i = 0; i < 8; ++i)
#pragma unroll
        for (int j = 0; j < 8; ++j) acc[i][j] = 0.f;

    for (int kt = kstart; kt < kend; kt += TKK) {
        // stage A tile (transposed into LDS): 128 rows x 16 k
#pragma unroll
        for (int l = 0; l < 2; ++l) {
            int idx = tid + l * 256;          // 0..511
            int r = idx >> 2, kq = idx & 3;
            float4 v = make_float4(0.f, 0.f, 0.f, 0.f);
            int gr = m0 + r;
            if (gr < M)
                v = *reinterpret_cast<const float4*>(A + (size_t)gr * K + kt + (kq << 2));
            As[(kq << 2) + 0][r] = v.x;
            As[(kq << 2) + 1][r] = v.y;
            As[(kq << 2) + 2][r] = v.z;
            As[(kq << 2) + 3][r] = v.w;
        }
        // stage B tile: 16 k x 128 n
#pragma unroll
        for (int l = 0; l < 2; ++l) {
            int idx = tid + l * 256;
            int kk = idx >> 5, nq = idx & 31;
            int gn = n0 + (nq << 2);
            const float* bp = B + (size_t)(kt + kk) * N + gn;
            float4 v;
            if (nvec && gn + 3 < N) {
                v = *reinterpret_cast<const float4*>(bp);
            } else {
                v.x = (gn + 0 < N) ? bp[0] : 0.f;
                v.y = (gn + 1 < N) ? bp[1] : 0.f;
                v.z = (gn + 2 < N) ? bp[2] : 0.f;
                v.w = (gn + 3 < N) ? bp[3] : 0.f;
            }
            *reinterpret_cast<float4*>(&Bs[kk][nq << 2]) = v;
        }
        __syncthreads();
#pragma unroll
        for (int kk = 0; kk < TKK; ++kk) {
            float a[8], b[8];
            *reinterpret_cast<float4*>(&a[0]) = *reinterpret_cast<const float4*>(&As[kk][ty * 8]);
            *reinterpret_cast<float4*>(&a[4]) = *reinterpret_cast<const float4*>(&As[kk][ty * 8 + 4]);
            *reinterpret_cast<float4*>(&b[0]) = *reinterpret_cast<const float4*>(&Bs[kk][tx * 8]);
            *reinterpret_cast<float4*>(&b[4]) = *reinterpret_cast<const float4*>(&Bs[kk][tx * 8 + 4]);
#pragma unroll
            for (int i = 0; i < 8; ++i)
#pragma unroll
                for (int j = 0; j < 8; ++j)
                    acc[i][j] = fmaf(a[i], b[j], acc[i][j]);
        }
        __syncthreads();
    }
#pragma unroll
    for (int i = 0; i < 8; ++i) {
        int gr = m0 + ty * 8 + i;
        if (gr >= M) continue;
#pragma unroll
        for (int j = 0; j < 8; ++j) {
            int gc = n0 + tx * 8 + j;
            if (gc >= N) continue;
            float v = acc[i][j];
            if (bias) v += bias[gc];
            if (relu) v = fmaxf(v, 0.f);
            Cz[(size_t)gr * N + gc] = v;
        }
    }
}

// ---------------- combine split-K partials + bias + relu ----------------
__global__ void combine_relu(const float* __restrict__ P, const float* __restrict__ bias,
                             float* __restrict__ H, int total4, int ncol4, int nsplit,
                             int pstride4)
{
    int i = blockIdx.x * blockDim.x + threadIdx.x;
    if (i >= total4) return;
    const float4* p = reinterpret_cast<const float4*>(P);
    float4 s = p[i];
    for (int j = 1; j < nsplit; ++j) {
        float4 q = p[i + (size_t)j * pstride4];
        s.x += q.x; s.y += q.y; s.z += q.z; s.w += q.w;
    }
    const float4 bb = *reinterpret_cast<const float4*>(bias + (size_t)(i % ncol4) * 4);
    s.x = fmaxf(s.x + bb.x, 0.f);
    s.y = fmaxf(s.y + bb.y, 0.f);
    s.z = fmaxf(s.z + bb.z, 0.f);
    s.w = fmaxf(s.w + bb.w, 0.f);
    reinterpret_cast<float4*>(H)[i] = s;
}

// Python int scalars may arrive as int32 or float32 single-element arrays — sniff bits.
__device__ __forceinline__ float scalar_dim(const int* p)
{
    int iv = *p;
    return (iv > 0 && iv < (1 << 20)) ? (float)iv : *reinterpret_cast<const float*>(p);
}

// ---------------- decode + softmax + threshold + compact ----------------
__global__ __launch_bounds__(128) void decode_compact(
    const float* __restrict__ logits, const float* __restrict__ breg,
    const float4* __restrict__ proposals, const int* __restrict__ ihp,
    const int* __restrict__ iwp,
    float* __restrict__ cscore, float4* __restrict__ cboxn, float4* __restrict__ cboxo,
    int* __restrict__ cidx, int* __restrict__ cnt)
{
    const int n = blockIdx.x;
    const int c = threadIdx.x;
    __shared__ float sl[91];
    __shared__ float s_max, s_sum;
    if (c < 91) sl[c] = logits[n * 91 + c];
    __syncthreads();
    if (c == 0) {
        float m = sl[0];
        for (int i = 1; i < 91; ++i) m = fmaxf(m, sl[i]);
        float s = 0.f;
        for (int i = 0; i < 91; ++i) s += expf(sl[i] - m);
        s_max = m; s_sum = s;
    }
    __syncthreads();
    if (c < 1 || c >= 91) return;

    const float score = expf(sl[c] - s_max) / s_sum;
    const float Wim = scalar_dim(iwp), Him = scalar_dim(ihp);
    float4 p = proposals[n];
    float pw = p.z - p.x, ph = p.w - p.y;
    float pcx = p.x + 0.5f * pw, pcy = p.y + 0.5f * ph;
    const float* r4 = breg + (size_t)n * 364 + c * 4;
    float dxv = r4[0] / 10.f, dyv = r4[1] / 10.f;
    const float BCLIP = 4.135166556742356f;   // log(1000/16) rounded to f32
    float dwv = fminf(r4[2] / 5.f, BCLIP);
    float dhv = fminf(r4[3] / 5.f, BCLIP);
    float cx = dxv * pw + pcx, cy = dyv * ph + pcy;
    float w = expf(dwv) * pw, hh = expf(dhv) * ph;
    float x1 = cx - 0.5f * w, y1 = cy - 0.5f * hh;
    float x2 = cx + 0.5f * w, y2 = cy + 0.5f * hh;
    x1 = fminf(fmaxf(x1, 0.f), Wim);
    y1 = fminf(fmaxf(y1, 0.f), Him);
    x2 = fminf(fmaxf(x2, 0.f), Wim);
    y2 = fminf(fmaxf(y2, 0.f), Him);
    float bw = x2 - x1, bh = y2 - y1;
    if (score > 0.05f && bw >= 0.01f && bh >= 0.01f) {
        int pos = atomicAdd(cnt, 1);
        if (pos < CAP) {
            float off = (float)c * (fmaxf(Wim, Him) + 1.f);
            cscore[pos] = score;
            cboxn[pos] = make_float4(x1 + off, y1 + off, x2 + off, y2 + off);
            cboxo[pos] = make_float4(x1, y1, x2, y2);
            cidx[pos] = n * 90 + (c - 1);
        }
    }
}

// ---------------- greedy NMS: iterated argmax over compacted candidates ----------------
__global__ __launch_bounds__(1024) void nms_kernel(
    float* __restrict__ sm, const float4* __restrict__ cboxn,
    const float4* __restrict__ cboxo, const int* __restrict__ cidx,
    const int* __restrict__ cnt, float* __restrict__ out)
{
    __shared__ float red_s[16];
    __shared__ int red_i[16];
    __shared__ float selb[5];
    __shared__ int sel_i;
    const int tid = threadIdx.x;
    int M = *cnt;
    if (M > CAP) M = CAP;

    for (int k = 0; k < 100; ++k) {
        // argmax with tie-break on smallest original flat index (jnp.argmax semantics)
        float best = -3.4e38f; int bi = -1; int bc = 0x7fffffff;
        for (int i = tid; i < M; i += 1024) {
            float v = sm[i];
            if (v > best) { best = v; bi = i; bc = cidx[i]; }
            else if (v == best) { int ci = cidx[i]; if (ci < bc) { bi = i; bc = ci; } }
        }
#pragma unroll
        for (int d = 32; d >= 1; d >>= 1) {
            float ob = __shfl_down(best, d, 64);
            int obi = __shfl_down(bi, d, 64);
            int obc = __shfl_down(bc, d, 64);
            if (ob > best || (ob == best && obc < bc)) { best = ob; bi = obi; bc = obc; }
        }
        if ((tid & 63) == 0) { red_s[tid >> 6] = best; red_i[tid >> 6] = bi; }
        __syncthreads();
        if (tid == 0) {
            float b2 = -3.4e38f; int i2 = -1; int c2 = 0x7fffffff;
            for (int wv = 0; wv < 16; ++wv) {
                float vv = red_s[wv]; int ii = red_i[wv];
                if (ii < 0) continue;
                int cc = cidx[ii];
                if (vv > b2 || (vv == b2 && cc < c2)) { b2 = vv; i2 = ii; c2 = cc; }
            }
            if (i2 >= 0 && b2 > NEGV * 0.5f) {
                float4 bo = cboxo[i2];
                out[k * 4 + 0] = bo.x; out[k * 4 + 1] = bo.y;
                out[k * 4 + 2] = bo.z; out[k * 4 + 3] = bo.w;
                out[400 + k] = b2;
                out[500 + k] = (float)((cidx[i2] % 90) + 1);
                float4 bn = cboxn[i2];
                selb[0] = bn.x; selb[1] = bn.y; selb[2] = bn.z; selb[3] = bn.w;
                selb[4] = (bn.z - bn.x) * (bn.w - bn.y);
                sel_i = i2;
            } else {
                out[k * 4 + 0] = 0.f; out[k * 4 + 1] = 0.f;
                out[k * 4 + 2] = 0.f; out[k * 4 + 3] = 0.f;
                out[400 + k] = 0.f; out[500 + k] = 0.f;
                sel_i = -1;
            }
        }
        __syncthreads();
        const int si = sel_i;
        if (si >= 0) {
            const float bx1 = selb[0], by1 = selb[1], bx2 = selb[2], by2 = selb[3];
            const float sa = selb[4];
            for (int i = tid; i < M; i += 1024) {
                float4 b = cboxn[i];
                float xx1 = fmaxf(bx1, b.x), yy1 = fmaxf(by1, b.y);
                float xx2 = fminf(bx2, b.z), yy2 = fminf(by2, b.w);
                float inter = fmaxf(xx2 - xx1, 0.f) * fmaxf(yy2 - yy1, 0.f);
                float area = (b.z - b.x) * (b.w - b.y);
                float iou = inter / (sa + area - inter + 1e-9f);
                if (iou > 0.5f || i == si) sm[i] = NEGV;
            }
        }
        __syncthreads();
    }
}

// ------------------------------------------------------------------------
extern "C" void kernel_launch(void* const* d_in, const int* in_sizes, int n_in,
                              void* d_out, int out_size, void* d_ws, size_t ws_size,
                              hipStream_t stream)
{
    const float* bf    = (const float*)d_in[0];
    const float* props = (const float*)d_in[1];
    const float* W1    = (const float*)d_in[2];
    const float* b1    = (const float*)d_in[3];
    const float* W2    = (const float*)d_in[4];
    const float* b2    = (const float*)d_in[5];
    const float* Wc    = (const float*)d_in[6];
    const float* bc    = (const float*)d_in[7];
    const float* Wr    = (const float*)d_in[8];
    const float* br    = (const float*)d_in[9];
    const int*   ihp   = (const int*)d_in[10];
    const int*   iwp   = (const int*)d_in[11];
    float* ws  = (float*)d_ws;
    float* out = (float*)d_out;

    const size_t MN = 2000ull * 1024ull;        // 2,048,000
    const size_t FIXED = MN /*H1*/ + MN /*H2*/ + 182000 /*LOG*/ + 728000 /*BREG*/
                       + (size_t)CAP * 10 + 4;  // compact arrays + cnt
    int nsplit = 1;
    if (ws_size >= (FIXED + 4 * MN) * 4) nsplit = 4;
    else if (ws_size >= (FIXED + 2 * MN) * 4) nsplit = 2;

    float* P    = ws;
    float* H1   = P + (size_t)nsplit * MN;
    float* H2   = H1 + MN;
    float* LOG  = H2 + MN;
    float* BREG = LOG + 182000;
    float* CS   = BREG + 728000;
    float* BN   = CS + CAP;
    float* BO   = BN + (size_t)CAP * 4;
    int*   CI   = (int*)(BO + (size_t)CAP * 4);
    int*   CNT  = CI + CAP;

    // 1) GEMM1 split-K partials: P[z] = bf @ W1[kslice]
    gemm_f32<<<dim3(8, 16, nsplit), 256, 0, stream>>>(bf, W1, nullptr, P,
                                                      2000, 1024, 12544, 12544 / nsplit, 0);
    // 2) H1 = relu(sum partials + b1)
    combine_relu<<<2000, 256, 0, stream>>>(P, b1, H1, (int)(MN / 4), 256, nsplit,
                                           (int)(MN / 4));
    // 3) H2 = relu(H1 @ W2 + b2)
    gemm_f32<<<dim3(8, 16, 1), 256, 0, stream>>>(H1, W2, b2, H2, 2000, 1024, 1024, 1024, 1);
    // 4) logits / box_reg heads
    gemm_f32<<<dim3(1, 16, 1), 256, 0, stream>>>(H2, Wc, bc, LOG, 2000, 91, 1024, 1024, 0);
    gemm_f32<<<dim3(3, 16, 1), 256, 0, stream>>>(H2, Wr, br, BREG, 2000, 364, 1024, 1024, 0);
    // 5) decode + softmax + threshold + compaction
    hipMemsetAsync(CNT, 0, sizeof(int), stream);
    decode_compact<<<2000, 128, 0, stream>>>(LOG, BREG, (const float4*)props, ihp, iwp,
                                             CS, (float4*)BN, (float4*)BO, CI, CNT);
    // 6) greedy NMS + output gather (boxes[400] | scores[100] | labels[100])
    nms_kernel<<<1, 1024, 0, stream>>>(CS, (const float4*)BN, (const float4*)BO, CI, CNT, out);
}